// Round 18
// baseline (95.839 us; speedup 1.0000x reference)
//
#include <hip/hip_runtime.h>
#include <hip/hip_bf16.h>

#define NB   16384
#define NG   8
#define ND   2048
#define NR   6
#define NKC  48
#define NOUT 54
#define LROW 136                  // tier-3 fallback gemm
#define BM   32
#define KC   128
#define NCH  (ND / KC)
#define MAXT (NB / BM + NG)

typedef __attribute__((ext_vector_type(8))) short short8_t;
typedef __attribute__((ext_vector_type(4))) float f32x4;

__device__ __forceinline__ unsigned short f2bf(float x) {
    union { float f; unsigned u; } v; v.f = x;
    unsigned r = v.u + 0x7FFFu + ((v.u >> 16) & 1u);   // RNE
    return (unsigned short)(r >> 16);
}

__device__ __forceinline__ short8_t cvt8(float4 a, float4 b) {
    short8_t s;
    s[0] = (short)f2bf(a.x); s[1] = (short)f2bf(a.y);
    s[2] = (short)f2bf(a.z); s[3] = (short)f2bf(a.w);
    s[4] = (short)f2bf(b.x); s[5] = (short)f2bf(b.y);
    s[6] = (short)f2bf(b.z); s[7] = (short)f2bf(b.w);
    return s;
}

__device__ __forceinline__ void gl_lds16(const void* g, void* s) {
    __builtin_amdgcn_global_load_lds(
        (const __attribute__((address_space(1))) void*)g,
        (__attribute__((address_space(3))) void*)s,
        16, 0, 0);
}

#define WAITV(N) do { asm volatile("s_waitcnt vmcnt(" #N ")" ::: "memory"); \
                      __builtin_amdgcn_sched_barrier(0); } while (0)
#define BAR() do { __builtin_amdgcn_s_barrier(); \
                   __builtin_amdgcn_sched_barrier(0); } while (0)

// ---- histogram (tier-3) ----
__global__ void hist_kernel(const int* __restrict__ roi, int* __restrict__ counts) {
    int i = blockIdx.x * 256 + threadIdx.x;
    int g = roi[i];
    int lane = threadIdx.x & 63;
    #pragma unroll
    for (int gg = 0; gg < NG; ++gg) {
        unsigned long long m = __ballot(g == gg);
        if (m && lane == (int)(__ffsll((unsigned long long)m) - 1))
            atomicAdd(&counts[gg], (int)__popcll(m));
    }
}

// ---- scatter into packed regions (tier-3) ----
__global__ void scatter_kernel(const int* __restrict__ roi, const int* __restrict__ counts,
                               int* __restrict__ ranks, int* __restrict__ perm) {
    int off[NG];
    int acc = 0;
    #pragma unroll
    for (int gg = 0; gg < NG; ++gg) { off[gg] = acc; acc += counts[gg]; }
    int i = blockIdx.x * 256 + threadIdx.x;
    int g = roi[i];
    int lane = threadIdx.x & 63;
    #pragma unroll
    for (int gg = 0; gg < NG; ++gg) {
        unsigned long long m = __ballot(g == gg);
        if (!m) continue;
        int leader = (int)(__ffsll((unsigned long long)m) - 1);
        int base = 0;
        if (lane == leader) base = atomicAdd(&ranks[gg], (int)__popcll(m));
        base = __shfl(base, leader);
        if (g == gg) {
            int rank = (int)__popcll(m & ((1ull << lane) - 1ull));
            perm[off[gg] + base + rank] = i;
        }
    }
}

// ---- prep: blocks 0..63 rank samples within group; 64..575 build W blob ----
// blob unit u (16B): l=u&63, q=(u>>6)&7, c=(u>>9)&31, g=u>>14; n=q>>1, ks=q&1
// content = W[g][n*16 + (l&15)][c*64 + ks*32 + (l>>4)*8 .. +8)
__global__ void prep_kernel(const int* __restrict__ roi, int* __restrict__ cnt,
                            int* __restrict__ rank,
                            const float* __restrict__ Wreg, const float* __restrict__ Wcls,
                            short* __restrict__ Wbf) {
    if (blockIdx.x < 64) {
        int i = blockIdx.x * 256 + threadIdx.x;
        int g = roi[i];
        int lane = threadIdx.x & 63;
        #pragma unroll
        for (int gg = 0; gg < NG; ++gg) {
            unsigned long long m = __ballot(g == gg);
            if (!m) continue;
            int leader = (int)(__ffsll((unsigned long long)m) - 1);
            int base = 0;
            if (lane == leader) base = atomicAdd(&cnt[gg], (int)__popcll(m));
            base = __shfl(base, leader);
            if (g == gg) {
                int r = (int)__popcll(m & ((1ull << lane) - 1ull));
                rank[i] = base + r;
            }
        }
    } else {
        int u = (blockIdx.x - 64) * 256 + threadIdx.x;   // 131072 units
        int l = u & 63;
        int q = (u >> 6) & 7;
        int c = (u >> 9) & 31;
        int g = u >> 14;
        int n = q >> 1, ks = q & 1;
        int row = n * 16 + (l & 15);
        int k   = c * 64 + ks * 32 + (l >> 4) * 8;
        short8_t v = {0, 0, 0, 0, 0, 0, 0, 0};
        if (row < NOUT) {
            const float* s = (row < NR) ? Wreg + (size_t)(g * NR + row) * ND + k
                                        : Wcls + (size_t)(g * NKC + row - NR) * ND + k;
            float4 a = *(const float4*)s;
            float4 b = *(const float4*)(s + 4);
            v = cvt8(a, b);
        }
        *(short8_t*)(Wbf + (size_t)u * 8) = v;
    }
}

// ---- castgather: index-ordered streaming read of feats (DRAM-optimal),
//      fp32->bf16, write row to packed sorted position (4KB contiguous) ----
__global__ void castgather_kernel(const float* __restrict__ feats,
                                  const int* __restrict__ roi,
                                  const int* __restrict__ cnt, const int* __restrict__ rank,
                                  short* __restrict__ gathered, int* __restrict__ permp) {
    int b = blockIdx.x;               // one block per sample, address order
    int tid = threadIdx.x;            // 256 threads x 8 floats = 2048
    int g = roi[b];
    int pre = 0;
    #pragma unroll
    for (int gg = 0; gg < NG; ++gg) if (gg < g) pre += cnt[gg];
    int pos = pre + rank[b];
    if (tid == 0) permp[pos] = b;
    const float* src = feats + (size_t)b * ND + tid * 8;
    float4 a0 = *(const float4*)(src);
    float4 a1 = *(const float4*)(src + 4);
    *(short8_t*)(gathered + (size_t)pos * ND + tid * 8) = cvt8(a0, a1);
}

// ---- primary GEMM: M=128 x N=64 tile, K-split 2, bf16 sorted A ----
// <=272 blocks x 8 waves (512 thr): b -> (tile t = b>>1, K-half kh = b&1).
// 16 chunks of KC=64 per block; per phase staged: A 16KB (2 gl_lds/wave, 8
// contiguous rows each, XOR involution) + B 8KB (1 gl_lds/wave from blob).
// Ring-3 24KB slots (72KB LDS, 2 blocks/CU), WAITV(6)/3/0, raw barriers.
// Wave w: rows 32*(w>>1)..+32, cols 32*(w&1)..+32. K-halves merge via
// atomicAdd on zeroed out (2 commutative adds -> deterministic); kh=0 adds bias.
__launch_bounds__(512, 2)
__global__ void gemm_w_kernel(const short* __restrict__ gathered,
                              const short* __restrict__ Wbf,
                              const float* __restrict__ breg, const float* __restrict__ bcls,
                              const int* __restrict__ cnt, const int* __restrict__ permp,
                              float* __restrict__ out) {
    __shared__ __align__(16) char lds[3][24576];   // slot: A 16KB @0 | B 8KB @16384

    int tid = threadIdx.x, w = tid >> 6, l = tid & 63, lr = l & 15, lq = l >> 4;
    int rw = w >> 1, ch = w & 1;

    int ts[NG + 1]; ts[0] = 0;
    int pre[NG]; int acc_ = 0;
    #pragma unroll
    for (int gg = 0; gg < NG; ++gg) {
        pre[gg] = acc_;
        acc_ += cnt[gg];
        ts[gg + 1] = ts[gg] + ((cnt[gg] + 127) >> 7);
    }
    int b = blockIdx.x;
    if (b >= 2 * ts[NG]) return;
    int t = b >> 1, kh = b & 1;
    int g = 0;
    #pragma unroll
    for (int gg = 0; gg < NG; ++gg) if (t >= ts[gg + 1]) g = gg + 1;
    int rbase = (t - ts[g]) * 128;
    int nv = cnt[g] - rbase; if (nv > 128) nv = 128;
    int t128 = pre[g] + rbase;       // packed base position of this tile

    // A staging: wave w stages rows 16w..16w+15 via 2 gl_lds (8 rows each).
    // gl_lds j: lane l -> row 16w+8j+(l>>3), piece (l&7)^(row&7).
    int r0 = 16 * w + (l >> 3);
    int r1 = r0 + 8;
    const char* a0c = (const char*)gathered + ((size_t)t128 + r0) * 4096 + kh * 2048
                    + (((l & 7) ^ (r0 & 7)) << 4);
    const char* a1c = (const char*)gathered + ((size_t)t128 + r1) * 4096 + kh * 2048
                    + (((l & 7) ^ (r1 & 7)) << 4);
    // B staging: wave w stages granule w (1KB) of each chunk
    const char* bSrc = (const char*)Wbf + ((size_t)(g * 32 + kh * 16) * 8 + w) * 1024 + l * 16;

#define STAGE(cc, sl) do {                                                     \
        gl_lds16(a0c + (size_t)(cc) * 128, &lds[sl][(16 * w) * 128]);          \
        gl_lds16(a1c + (size_t)(cc) * 128, &lds[sl][(16 * w + 8) * 128]);      \
        gl_lds16(bSrc + (size_t)(cc) * 8192, &lds[sl][16384 + w * 1024]);      \
    } while (0)

    // A read offsets: row R = rw*32 + mt*16 + lr (R&7 == lr&7);
    // piece p = (ks*4+lq) ^ (lr&7); off = R*128 + p*16
    const int key = lr & 7;
    const int Rb0 = (rw * 32 + lr) * 128;          // mt=0
    const int Rb1 = (rw * 32 + 16 + lr) * 128;     // mt=1
    const int ra00 = Rb0 + (((0 * 4 + lq) ^ key) << 4);
    const int ra01 = Rb0 + (((1 * 4 + lq) ^ key) << 4);
    const int ra10 = Rb1 + (((0 * 4 + lq) ^ key) << 4);
    const int ra11 = Rb1 + (((1 * 4 + lq) ^ key) << 4);
    // B read offsets: granule q = (ch*2+cn)*2 + ks
    const int rb00 = 16384 + ((ch * 2 + 0) * 2 + 0) * 1024 + l * 16;
    const int rb01 = 16384 + ((ch * 2 + 0) * 2 + 1) * 1024 + l * 16;
    const int rb10 = 16384 + ((ch * 2 + 1) * 2 + 0) * 1024 + l * 16;
    const int rb11 = 16384 + ((ch * 2 + 1) * 2 + 1) * 1024 + l * 16;

    f32x4 acc00 = {0,0,0,0}, acc01 = {0,0,0,0}, acc10 = {0,0,0,0}, acc11 = {0,0,0,0};

    STAGE(0, 0); STAGE(1, 1);          // 6 outstanding per wave
    int csl = 0;
    #pragma unroll
    for (int c = 0; c < 16; ++c) {
        if (c + 2 < 16) STAGE(c + 2, (c + 2) % 3);   // 9 outstanding
        if (c < 14)       WAITV(6);                  // chunk c landed; 2 in flight
        else if (c == 14) WAITV(3);
        else              WAITV(0);
        BAR();
        {
            const char* s = &lds[csl][0];
            short8_t af00 = *(const short8_t*)(s + ra00);   // mt0 ks0
            short8_t af10 = *(const short8_t*)(s + ra10);   // mt1 ks0
            short8_t b00  = *(const short8_t*)(s + rb00);   // cn0 ks0
            short8_t b10  = *(const short8_t*)(s + rb10);   // cn1 ks0
            acc00 = __builtin_amdgcn_mfma_f32_16x16x32_bf16(af00, b00, acc00, 0, 0, 0);
            acc01 = __builtin_amdgcn_mfma_f32_16x16x32_bf16(af00, b10, acc01, 0, 0, 0);
            acc10 = __builtin_amdgcn_mfma_f32_16x16x32_bf16(af10, b00, acc10, 0, 0, 0);
            acc11 = __builtin_amdgcn_mfma_f32_16x16x32_bf16(af10, b10, acc11, 0, 0, 0);
            short8_t af01 = *(const short8_t*)(s + ra01);   // mt0 ks1
            short8_t af11 = *(const short8_t*)(s + ra11);   // mt1 ks1
            short8_t b01  = *(const short8_t*)(s + rb01);   // cn0 ks1
            short8_t b11  = *(const short8_t*)(s + rb11);   // cn1 ks1
            acc00 = __builtin_amdgcn_mfma_f32_16x16x32_bf16(af01, b01, acc00, 0, 0, 0);
            acc01 = __builtin_amdgcn_mfma_f32_16x16x32_bf16(af01, b11, acc01, 0, 0, 0);
            acc10 = __builtin_amdgcn_mfma_f32_16x16x32_bf16(af11, b01, acc10, 0, 0, 0);
            acc11 = __builtin_amdgcn_mfma_f32_16x16x32_bf16(af11, b11, acc11, 0, 0, 0);
        }
        BAR();
        csl = (csl == 2) ? 0 : csl + 1;
    }
#undef STAGE

    // epilogue: atomic merge (+bias on half 0) to routed rows
    const int B6 = NB * NR;
    #pragma unroll
    for (int mt = 0; mt < 2; ++mt) {
        #pragma unroll
        for (int cn = 0; cn < 2; ++cn) {
            f32x4 v = (mt == 0) ? (cn == 0 ? acc00 : acc01) : (cn == 0 ? acc10 : acc11);
            int col = ch * 32 + cn * 16 + lr;
            if (col < NOUT) {
                float bias = 0.f;
                if (kh == 0) bias = (col < NR) ? breg[g * NR + col] : bcls[g * NKC + (col - NR)];
                #pragma unroll
                for (int j = 0; j < 4; ++j) {
                    int row = rw * 32 + mt * 16 + lq * 4 + j;
                    if (row < nv) {
                        int smp = permp[t128 + row];
                        if (col < NR) atomicAdd(&out[smp * NR + col], v[j] + bias);
                        else          atomicAdd(&out[B6 + smp * NKC + (col - NR)], v[j] + bias);
                    }
                }
            }
        }
    }
}

// ---- tier-3 GEMM (proven R3 path, no ws blob needed) ----
__launch_bounds__(256, 3)
__global__ void gemm_kernel(const float* __restrict__ feats,
                            const float* __restrict__ Wreg, const float* __restrict__ breg,
                            const float* __restrict__ Wcls, const float* __restrict__ bcls,
                            const int* __restrict__ counts, const int* __restrict__ perm,
                            float* __restrict__ out, int stride) {
    __shared__ __align__(16) short Bsh[2][64][LROW];
    __shared__ int sRow[BM];

    int ts[NG + 1]; ts[0] = 0;
    int off[NG]; int acc = 0;
    #pragma unroll
    for (int gg = 0; gg < NG; ++gg) {
        int c = counts[gg];
        off[gg] = stride ? gg * stride : acc;
        acc += c;
        ts[gg + 1] = ts[gg] + (c + BM - 1) / BM;
    }
    int b = blockIdx.x;
    if (b >= ts[NG]) return;
    int g = 0;
    #pragma unroll
    for (int gg = 0; gg < NG; ++gg) if (b >= ts[gg + 1]) g = gg + 1;
    int gcnt  = counts[g];
    int goff  = off[g];
    int rbase = (b - ts[g]) * BM;
    int nvalid = gcnt - rbase; if (nvalid > BM) nvalid = BM;

    int tid = threadIdx.x;
    if (tid < BM) {
        int r = rbase + tid;
        if (r >= gcnt) r = gcnt - 1;
        sRow[tid] = perm[goff + r];
    }
    __syncthreads();

    int rB = tid >> 2;
    int cq = tid & 3;
    const float* wsrc = nullptr;
    if (rB < NR)        wsrc = Wreg + ((size_t)g * NR + rB) * ND + cq * 32;
    else if (rB < NOUT) wsrc = Wcls + ((size_t)g * NKC + (rB - NR)) * ND + cq * 32;

    int w = tid >> 6, l = tid & 63, lr = l & 15, lq = l >> 4;
    int mt = w & 1, nh = w >> 1;
    const float* aptr = feats + (size_t)sRow[mt * 16 + lr] * ND + lq * 8;
    const short* brp = (const short*)&Bsh[0][0][0] + (nh * 32 + lr) * LROW + lq * 8;

    f32x4 acc0 = {0, 0, 0, 0}, acc1 = {0, 0, 0, 0};
    float4 rb[8];

    if (wsrc) {
        #pragma unroll
        for (int i = 0; i < 8; ++i) rb[i] = *(const float4*)(wsrc + 4 * i);
    } else {
        #pragma unroll
        for (int i = 0; i < 8; ++i) rb[i] = make_float4(0.f, 0.f, 0.f, 0.f);
    }
    {
        short* bw = &Bsh[0][rB][cq * 32];
        #pragma unroll
        for (int j = 0; j < 4; ++j) *(short8_t*)(bw + 8 * j) = cvt8(rb[2 * j], rb[2 * j + 1]);
    }
    __syncthreads();

    #pragma unroll
    for (int c = 0; c < NCH; ++c) {
        const int cur = c & 1, nxt = cur ^ 1;
        if (c + 1 < NCH && wsrc) {
            const float* s = wsrc + (c + 1) * KC;
            #pragma unroll
            for (int i = 0; i < 8; ++i) rb[i] = *(const float4*)(s + 4 * i);
        }
        const short* bp = brp + cur * (64 * LROW);
        const float* ap = aptr + c * KC;
        #pragma unroll
        for (int ks = 0; ks < 4; ++ks) {
            float4 a0 = *(const float4*)(ap + ks * 32);
            float4 a1 = *(const float4*)(ap + ks * 32 + 4);
            short8_t af = cvt8(a0, a1);
            short8_t b0 = *(const short8_t*)(bp + ks * 32);
            short8_t b1 = *(const short8_t*)(bp + 16 * LROW + ks * 32);
            acc0 = __builtin_amdgcn_mfma_f32_16x16x32_bf16(af, b0, acc0, 0, 0, 0);
            acc1 = __builtin_amdgcn_mfma_f32_16x16x32_bf16(af, b1, acc1, 0, 0, 0);
        }
        if (c + 1 < NCH && wsrc) {
            short* bw = &Bsh[nxt][rB][cq * 32];
            #pragma unroll
            for (int j = 0; j < 4; ++j) *(short8_t*)(bw + 8 * j) = cvt8(rb[2 * j], rb[2 * j + 1]);
        } else if (c + 1 < NCH) {
            short8_t z = {0,0,0,0,0,0,0,0};
            short* bw = &Bsh[nxt][rB][cq * 32];
            #pragma unroll
            for (int j = 0; j < 4; ++j) *(short8_t*)(bw + 8 * j) = z;
        }
        __syncthreads();
    }

    const int B6 = NB * NR;
    #pragma unroll
    for (int n = 0; n < 2; ++n) {
        f32x4 v = n ? acc1 : acc0;
        int col = nh * 32 + n * 16 + lr;
        if (col < NOUT) {
            #pragma unroll
            for (int j = 0; j < 4; ++j) {
                int row = mt * 16 + lq * 4 + j;
                if (row < nvalid) {
                    int smp = sRow[row];
                    if (col < NR) out[smp * NR + col] = v[j] + breg[g * NR + col];
                    else          out[B6 + smp * NKC + (col - NR)] = v[j] + bcls[g * NKC + (col - NR)];
                }
            }
        }
    }
}

// ---- tier-4: exact fp32, one wave per sample ----
__global__ void fallback_kernel(const float* __restrict__ feats, const int* __restrict__ roi,
                                const float* __restrict__ Wreg, const float* __restrict__ breg,
                                const float* __restrict__ Wcls, const float* __restrict__ bcls,
                                float* __restrict__ out) {
    int i = blockIdx.x;
    int lane = threadIdx.x;
    int g = roi[i];
    const float* frow = feats + (size_t)i * ND;
    float f[32];
    #pragma unroll
    for (int q = 0; q < 32; ++q) f[q] = frow[lane + 64 * q];
    for (int o = 0; o < NOUT; ++o) {
        const float* wrow = (o < NR) ? Wreg + ((size_t)g * NR + o) * ND
                                     : Wcls + ((size_t)g * NKC + (o - NR)) * ND;
        float p = 0.f;
        #pragma unroll
        for (int q = 0; q < 32; ++q) p += f[q] * wrow[lane + 64 * q];
        #pragma unroll
        for (int s = 32; s; s >>= 1) p += __shfl_xor(p, s);
        if (lane == 0) {
            if (o < NR) out[i * NR + o] = p + breg[g * NR + o];
            else        out[NB * NR + i * NKC + (o - NR)] = p + bcls[g * NKC + (o - NR)];
        }
    }
}

extern "C" void kernel_launch(void* const* d_in, const int* in_sizes, int n_in,
                              void* d_out, int out_size, void* d_ws, size_t ws_size,
                              hipStream_t stream) {
    const float* feats = (const float*)d_in[0];
    const int*   roi   = (const int*)d_in[1];
    const float* Wreg  = (const float*)d_in[2];
    const float* breg  = (const float*)d_in[3];
    const float* Wcls  = (const float*)d_in[4];
    const float* bcls  = (const float*)d_in[5];
    float* out = (float*)d_out;

    const size_t cntOff  = 2u * 1024 * 1024;          // 64 ints
    const size_t rankOff = cntOff + 256;              // NB ints
    const size_t permOff = rankOff + (size_t)NB * 4;  // NB ints
    const size_t gathOff = 4u * 1024 * 1024;          // (NB+128) x 4KB bf16 rows
    const size_t need_t1 = gathOff + (size_t)(NB + 128) * 4096;
    const size_t need_t3 = 256 + (size_t)NB * 4;

    if (ws_size >= need_t1) {
        short* Wbf      = (short*)d_ws;
        int*   cnt      = (int*)((char*)d_ws + cntOff);
        int*   rank     = (int*)((char*)d_ws + rankOff);
        int*   permp    = (int*)((char*)d_ws + permOff);
        short* gathered = (short*)((char*)d_ws + gathOff);
        hipMemsetAsync(out, 0, (size_t)out_size * sizeof(float), stream);
        hipMemsetAsync(cnt, 0, 64, stream);
        prep_kernel<<<576, 256, 0, stream>>>(roi, cnt, rank, Wreg, Wcls, Wbf);
        castgather_kernel<<<NB, 256, 0, stream>>>(feats, roi, cnt, rank, gathered, permp);
        gemm_w_kernel<<<272, 512, 0, stream>>>(gathered, Wbf, breg, bcls, cnt, permp, out);
    } else if (ws_size >= need_t3) {
        int* counts = (int*)d_ws;
        int* ranks  = counts + 8;
        int* perm   = counts + 64;
        hipMemsetAsync(counts, 0, 16 * sizeof(int), stream);
        hist_kernel<<<NB / 256, 256, 0, stream>>>(roi, counts);
        scatter_kernel<<<NB / 256, 256, 0, stream>>>(roi, counts, ranks, perm);
        gemm_kernel<<<MAXT, 256, 0, stream>>>(feats, Wreg, breg, Wcls, bcls, counts, perm, out, 0);
    } else {
        fallback_kernel<<<NB, 64, 0, stream>>>(feats, roi, Wreg, breg, Wcls, bcls, out);
    }
}

// Round 19
// 78.278 us; speedup vs baseline: 1.2243x; 1.2243x over previous
//
#include <hip/hip_runtime.h>
#include <hip/hip_bf16.h>

#define NB   16384
#define NG   8
#define ND   2048
#define NR   6
#define NKC  48
#define NOUT 54
#define LROW 136                  // tier-3 fallback gemm
#define BM   32
#define KC   128
#define NCH  (ND / KC)
#define MAXT (NB / BM + NG)

typedef __attribute__((ext_vector_type(8))) short short8_t;
typedef __attribute__((ext_vector_type(4))) float f32x4;

__device__ __forceinline__ unsigned short f2bf(float x) {
    union { float f; unsigned u; } v; v.f = x;
    unsigned r = v.u + 0x7FFFu + ((v.u >> 16) & 1u);   // RNE
    return (unsigned short)(r >> 16);
}

__device__ __forceinline__ short8_t cvt8(float4 a, float4 b) {
    short8_t s;
    s[0] = (short)f2bf(a.x); s[1] = (short)f2bf(a.y);
    s[2] = (short)f2bf(a.z); s[3] = (short)f2bf(a.w);
    s[4] = (short)f2bf(b.x); s[5] = (short)f2bf(b.y);
    s[6] = (short)f2bf(b.z); s[7] = (short)f2bf(b.w);
    return s;
}

__device__ __forceinline__ void gl_lds16(const void* g, void* s) {
    __builtin_amdgcn_global_load_lds(
        (const __attribute__((address_space(1))) void*)g,
        (__attribute__((address_space(3))) void*)s,
        16, 0, 0);
}

#define WAITV(N) do { asm volatile("s_waitcnt vmcnt(" #N ")" ::: "memory"); \
                      __builtin_amdgcn_sched_barrier(0); } while (0)
#define BAR() do { __builtin_amdgcn_s_barrier(); \
                   __builtin_amdgcn_sched_barrier(0); } while (0)

// ---- histogram (tier-3) ----
__global__ void hist_kernel(const int* __restrict__ roi, int* __restrict__ counts) {
    int i = blockIdx.x * 256 + threadIdx.x;
    int g = roi[i];
    int lane = threadIdx.x & 63;
    #pragma unroll
    for (int gg = 0; gg < NG; ++gg) {
        unsigned long long m = __ballot(g == gg);
        if (m && lane == (int)(__ffsll((unsigned long long)m) - 1))
            atomicAdd(&counts[gg], (int)__popcll(m));
    }
}

// ---- scatter into packed regions (tier-3) ----
__global__ void scatter_kernel(const int* __restrict__ roi, const int* __restrict__ counts,
                               int* __restrict__ ranks, int* __restrict__ perm) {
    int off[NG];
    int acc = 0;
    #pragma unroll
    for (int gg = 0; gg < NG; ++gg) { off[gg] = acc; acc += counts[gg]; }
    int i = blockIdx.x * 256 + threadIdx.x;
    int g = roi[i];
    int lane = threadIdx.x & 63;
    #pragma unroll
    for (int gg = 0; gg < NG; ++gg) {
        unsigned long long m = __ballot(g == gg);
        if (!m) continue;
        int leader = (int)(__ffsll((unsigned long long)m) - 1);
        int base = 0;
        if (lane == leader) base = atomicAdd(&ranks[gg], (int)__popcll(m));
        base = __shfl(base, leader);
        if (g == gg) {
            int rank = (int)__popcll(m & ((1ull << lane) - 1ull));
            perm[off[gg] + base + rank] = i;
        }
    }
}

// ---- merged pre-pass: blocks 0..63 scatter roi; 64..575 build the W blob ----
// blob unit u (16B): l=u&63, q=(u>>6)&7, c=(u>>9)&31, g=u>>14; n=q>>1, ks=q&1
// content = W[g][n*16 + (l&15)][c*64 + ks*32 + (l>>4)*8 .. +8)
__global__ void prep_kernel(const int* __restrict__ roi, int* __restrict__ cnt,
                            int* __restrict__ perm,
                            const float* __restrict__ Wreg, const float* __restrict__ Wcls,
                            short* __restrict__ Wbf) {
    if (blockIdx.x < 64) {
        int i = blockIdx.x * 256 + threadIdx.x;
        int g = roi[i];
        int lane = threadIdx.x & 63;
        #pragma unroll
        for (int gg = 0; gg < NG; ++gg) {
            unsigned long long m = __ballot(g == gg);
            if (!m) continue;
            int leader = (int)(__ffsll((unsigned long long)m) - 1);
            int base = 0;
            if (lane == leader) base = atomicAdd(&cnt[gg], (int)__popcll(m));
            base = __shfl(base, leader);
            if (g == gg) {
                int rank = (int)__popcll(m & ((1ull << lane) - 1ull));
                perm[gg * NB + base + rank] = i;
            }
        }
    } else {
        int u = (blockIdx.x - 64) * 256 + threadIdx.x;   // 131072 units
        int l = u & 63;
        int q = (u >> 6) & 7;
        int c = (u >> 9) & 31;
        int g = u >> 14;
        int n = q >> 1, ks = q & 1;
        int row = n * 16 + (l & 15);
        int k   = c * 64 + ks * 32 + (l >> 4) * 8;
        short8_t v = {0, 0, 0, 0, 0, 0, 0, 0};
        if (row < NOUT) {
            const float* s = (row < NR) ? Wreg + (size_t)(g * NR + row) * ND + k
                                        : Wcls + (size_t)(g * NKC + row - NR) * ND + k;
            float4 a = *(const float4*)s;
            float4 b = *(const float4*)(s + 4);
            v = cvt8(a, b);
        }
        *(short8_t*)(Wbf + (size_t)u * 8) = v;
    }
}

// ---- primary: M=64 K-split-2 GEMM, ring-3 LDS, 2 blocks/CU (R14 + ring fix) ----
// 528 blocks x 8 waves (512 thr): item = (tile t, K-half kh). Tile = 64 samples
// x 64 cols; K-half = 1024 = 16 chunks of KC=64. Chunk = A 16KB + B 8KB.
// Wave w stages rows 8w..8w+7 (2 gl_lds) + B granule w (1 gl_lds). Ring-3
// slots (74KB LDS -> 2 blocks/CU, all CUs busy), 2-ahead prefetch,
// WAITV(6)/3/0. K-halves merge via atomicAdd on zeroed out (2 commutative
// contributions -> deterministic). Half 0 adds bias.
__launch_bounds__(512, 2)
__global__ void gemm_r3_kernel(const float* __restrict__ feats,
                               const short* __restrict__ Wbf,
                               const float* __restrict__ breg, const float* __restrict__ bcls,
                               const int* __restrict__ cnt, const int* __restrict__ perm,
                               float* __restrict__ out) {
    __shared__ __align__(16) char lds[3][24576];   // slot: A 16KB @0 | B 8KB @16384
    __shared__ int sRow[64];

    int tid = threadIdx.x, w = tid >> 6, l = tid & 63, lr = l & 15, lq = l >> 4;
    int rw = w >> 1, ch = w & 1;

    int ts[NG + 1]; ts[0] = 0;
    #pragma unroll
    for (int gg = 0; gg < NG; ++gg) ts[gg + 1] = ts[gg] + ((cnt[gg] + 63) >> 6);
    int item = blockIdx.x;
    if (item >= 2 * ts[NG]) return;
    int t = item >> 1, kh = item & 1;
    int g = 0;
    #pragma unroll
    for (int gg = 0; gg < NG; ++gg) if (t >= ts[gg + 1]) g = gg + 1;
    int cg = cnt[g];
    int rbase = (t - ts[g]) * 64;
    int nv = cg - rbase; if (nv > 64) nv = 64;

    if (tid < 64) {
        int r = rbase + tid;
        if (r >= cg) r = cg - 1;      // clamp; stores masked by nv
        sRow[tid] = perm[g * NB + r];
    }
    __syncthreads();

    // staging sources (XOR-involution pre-swizzled global pieces)
    int r0 = 8 * w + (l >> 4), r1 = r0 + 4;
    const char* a0c = (const char*)(feats + (size_t)sRow[r0] * ND) + kh * 4096
                    + (((l & 15) ^ (r0 & 7)) << 4);
    const char* a1c = (const char*)(feats + (size_t)sRow[r1] * ND) + kh * 4096
                    + (((l & 15) ^ (r1 & 7)) << 4);
    const char* bSrc = (const char*)Wbf + ((size_t)(g * 32 + kh * 16) * 8 + w) * 1024 + l * 16;

#define STAGE(cc, sl) do {                                                     \
        gl_lds16(a0c + (size_t)(cc) * 256,  &lds[sl][w * 2048]);               \
        gl_lds16(a1c + (size_t)(cc) * 256,  &lds[sl][w * 2048 + 1024]);        \
        gl_lds16(bSrc + (size_t)(cc) * 8192, &lds[sl][16384 + w * 1024]);      \
    } while (0)

    f32x4 acc0 = {0, 0, 0, 0}, acc1 = {0, 0, 0, 0};

    STAGE(0, 0); STAGE(1, 1);          // 6 outstanding per wave

    const int abase = (rw * 16 + lr) * 256;
    const int key = lr & 7;                                // (rw*16+lr)&7 == lr&7
    const int bq0 = 16384 + ((2 * ch + 0) * 2) * 1024 + l * 16;   // n=2ch,   ks=0
    const int bq1 = 16384 + ((2 * ch + 1) * 2) * 1024 + l * 16;   // n=2ch+1, ks=0

    #pragma unroll
    for (int c = 0; c < 16; ++c) {
        const int sl = c % 3;
        if (c + 2 < 16) STAGE(c + 2, (c + 2) % 3);   // 9 outstanding
        if (c < 14)       WAITV(6);                  // chunk c landed; 2 in flight
        else if (c == 14) WAITV(3);
        else              WAITV(0);
        BAR();
        {
            const char* s = &lds[sl][0];
            // ks = 0
            float4 a0 = *(const float4*)(s + abase + (((lq * 2 + 0) ^ key) << 4));
            float4 a1 = *(const float4*)(s + abase + (((lq * 2 + 1) ^ key) << 4));
            short8_t af0 = cvt8(a0, a1);
            short8_t b00 = *(const short8_t*)(s + bq0);
            short8_t b10 = *(const short8_t*)(s + bq1);
            acc0 = __builtin_amdgcn_mfma_f32_16x16x32_bf16(af0, b00, acc0, 0, 0, 0);
            acc1 = __builtin_amdgcn_mfma_f32_16x16x32_bf16(af0, b10, acc1, 0, 0, 0);
            // ks = 1
            float4 a2 = *(const float4*)(s + abase + (((8 + lq * 2 + 0) ^ key) << 4));
            float4 a3 = *(const float4*)(s + abase + (((8 + lq * 2 + 1) ^ key) << 4));
            short8_t af1 = cvt8(a2, a3);
            short8_t b01 = *(const short8_t*)(s + bq0 + 1024);
            short8_t b11 = *(const short8_t*)(s + bq1 + 1024);
            acc0 = __builtin_amdgcn_mfma_f32_16x16x32_bf16(af1, b01, acc0, 0, 0, 0);
            acc1 = __builtin_amdgcn_mfma_f32_16x16x32_bf16(af1, b11, acc1, 0, 0, 0);
        }
        BAR();
    }
#undef STAGE

    // epilogue: atomic merge (+bias on half 0) to routed rows
    const int B6 = NB * NR;
    #pragma unroll
    for (int cn = 0; cn < 2; ++cn) {
        f32x4 v = cn ? acc1 : acc0;
        int col = ch * 32 + cn * 16 + lr;
        if (col < NOUT) {
            float bias = 0.f;
            if (kh == 0) bias = (col < NR) ? breg[g * NR + col] : bcls[g * NKC + (col - NR)];
            #pragma unroll
            for (int j = 0; j < 4; ++j) {
                int row = rw * 16 + lq * 4 + j;
                if (row < nv) {
                    int smp = sRow[row];
                    if (col < NR) atomicAdd(&out[smp * NR + col], v[j] + bias);
                    else          atomicAdd(&out[B6 + smp * NKC + (col - NR)], v[j] + bias);
                }
            }
        }
    }
}

// ---- tier-3 GEMM (proven R3 path, no ws blob needed) ----
__launch_bounds__(256, 3)
__global__ void gemm_kernel(const float* __restrict__ feats,
                            const float* __restrict__ Wreg, const float* __restrict__ breg,
                            const float* __restrict__ Wcls, const float* __restrict__ bcls,
                            const int* __restrict__ counts, const int* __restrict__ perm,
                            float* __restrict__ out, int stride) {
    __shared__ __align__(16) short Bsh[2][64][LROW];
    __shared__ int sRow[BM];

    int ts[NG + 1]; ts[0] = 0;
    int off[NG]; int acc = 0;
    #pragma unroll
    for (int gg = 0; gg < NG; ++gg) {
        int c = counts[gg];
        off[gg] = stride ? gg * stride : acc;
        acc += c;
        ts[gg + 1] = ts[gg] + (c + BM - 1) / BM;
    }
    int b = blockIdx.x;
    if (b >= ts[NG]) return;
    int g = 0;
    #pragma unroll
    for (int gg = 0; gg < NG; ++gg) if (b >= ts[gg + 1]) g = gg + 1;
    int gcnt  = counts[g];
    int goff  = off[g];
    int rbase = (b - ts[g]) * BM;
    int nvalid = gcnt - rbase; if (nvalid > BM) nvalid = BM;

    int tid = threadIdx.x;
    if (tid < BM) {
        int r = rbase + tid;
        if (r >= gcnt) r = gcnt - 1;
        sRow[tid] = perm[goff + r];
    }
    __syncthreads();

    int rB = tid >> 2;
    int cq = tid & 3;
    const float* wsrc = nullptr;
    if (rB < NR)        wsrc = Wreg + ((size_t)g * NR + rB) * ND + cq * 32;
    else if (rB < NOUT) wsrc = Wcls + ((size_t)g * NKC + (rB - NR)) * ND + cq * 32;

    int w = tid >> 6, l = tid & 63, lr = l & 15, lq = l >> 4;
    int mt = w & 1, nh = w >> 1;
    const float* aptr = feats + (size_t)sRow[mt * 16 + lr] * ND + lq * 8;
    const short* brp = (const short*)&Bsh[0][0][0] + (nh * 32 + lr) * LROW + lq * 8;

    f32x4 acc0 = {0, 0, 0, 0}, acc1 = {0, 0, 0, 0};
    float4 rb[8];

    if (wsrc) {
        #pragma unroll
        for (int i = 0; i < 8; ++i) rb[i] = *(const float4*)(wsrc + 4 * i);
    } else {
        #pragma unroll
        for (int i = 0; i < 8; ++i) rb[i] = make_float4(0.f, 0.f, 0.f, 0.f);
    }
    {
        short* bw = &Bsh[0][rB][cq * 32];
        #pragma unroll
        for (int j = 0; j < 4; ++j) *(short8_t*)(bw + 8 * j) = cvt8(rb[2 * j], rb[2 * j + 1]);
    }
    __syncthreads();

    #pragma unroll
    for (int c = 0; c < NCH; ++c) {
        const int cur = c & 1, nxt = cur ^ 1;
        if (c + 1 < NCH && wsrc) {
            const float* s = wsrc + (c + 1) * KC;
            #pragma unroll
            for (int i = 0; i < 8; ++i) rb[i] = *(const float4*)(s + 4 * i);
        }
        const short* bp = brp + cur * (64 * LROW);
        const float* ap = aptr + c * KC;
        #pragma unroll
        for (int ks = 0; ks < 4; ++ks) {
            float4 a0 = *(const float4*)(ap + ks * 32);
            float4 a1 = *(const float4*)(ap + ks * 32 + 4);
            short8_t af = cvt8(a0, a1);
            short8_t b0 = *(const short8_t*)(bp + ks * 32);
            short8_t b1 = *(const short8_t*)(bp + 16 * LROW + ks * 32);
            acc0 = __builtin_amdgcn_mfma_f32_16x16x32_bf16(af, b0, acc0, 0, 0, 0);
            acc1 = __builtin_amdgcn_mfma_f32_16x16x32_bf16(af, b1, acc1, 0, 0, 0);
        }
        if (c + 1 < NCH && wsrc) {
            short* bw = &Bsh[nxt][rB][cq * 32];
            #pragma unroll
            for (int j = 0; j < 4; ++j) *(short8_t*)(bw + 8 * j) = cvt8(rb[2 * j], rb[2 * j + 1]);
        } else if (c + 1 < NCH) {
            short8_t z = {0,0,0,0,0,0,0,0};
            short* bw = &Bsh[nxt][rB][cq * 32];
            #pragma unroll
            for (int j = 0; j < 4; ++j) *(short8_t*)(bw + 8 * j) = z;
        }
        __syncthreads();
    }

    const int B6 = NB * NR;
    #pragma unroll
    for (int n = 0; n < 2; ++n) {
        f32x4 v = n ? acc1 : acc0;
        int col = nh * 32 + n * 16 + lr;
        if (col < NOUT) {
            #pragma unroll
            for (int j = 0; j < 4; ++j) {
                int row = mt * 16 + lq * 4 + j;
                if (row < nvalid) {
                    int smp = sRow[row];
                    if (col < NR) out[smp * NR + col] = v[j] + breg[g * NR + col];
                    else          out[B6 + smp * NKC + (col - NR)] = v[j] + bcls[g * NKC + (col - NR)];
                }
            }
        }
    }
}

// ---- tier-4: exact fp32, one wave per sample ----
__global__ void fallback_kernel(const float* __restrict__ feats, const int* __restrict__ roi,
                                const float* __restrict__ Wreg, const float* __restrict__ breg,
                                const float* __restrict__ Wcls, const float* __restrict__ bcls,
                                float* __restrict__ out) {
    int i = blockIdx.x;
    int lane = threadIdx.x;
    int g = roi[i];
    const float* frow = feats + (size_t)i * ND;
    float f[32];
    #pragma unroll
    for (int q = 0; q < 32; ++q) f[q] = frow[lane + 64 * q];
    for (int o = 0; o < NOUT; ++o) {
        const float* wrow = (o < NR) ? Wreg + ((size_t)g * NR + o) * ND
                                     : Wcls + ((size_t)g * NKC + (o - NR)) * ND;
        float p = 0.f;
        #pragma unroll
        for (int q = 0; q < 32; ++q) p += f[q] * wrow[lane + 64 * q];
        #pragma unroll
        for (int s = 32; s; s >>= 1) p += __shfl_xor(p, s);
        if (lane == 0) {
            if (o < NR) out[i * NR + o] = p + breg[g * NR + o];
            else        out[NB * NR + i * NKC + (o - NR)] = p + bcls[g * NKC + (o - NR)];
        }
    }
}

extern "C" void kernel_launch(void* const* d_in, const int* in_sizes, int n_in,
                              void* d_out, int out_size, void* d_ws, size_t ws_size,
                              hipStream_t stream) {
    const float* feats = (const float*)d_in[0];
    const int*   roi   = (const int*)d_in[1];
    const float* Wreg  = (const float*)d_in[2];
    const float* breg  = (const float*)d_in[3];
    const float* Wcls  = (const float*)d_in[4];
    const float* bcls  = (const float*)d_in[5];
    float* out = (float*)d_out;

    const size_t wbfBytes = (size_t)NG * 131072 * 2;              // 2 MB blob
    const size_t need_t1 = wbfBytes + 256 + (size_t)NG * NB * 4;  // blob + fixed-stride perm
    const size_t need_t3 = 256 + (size_t)NB * 4;                  // packed-perm path

    if (ws_size >= need_t1) {
        short* Wbf = (short*)d_ws;
        int* cnt   = (int*)((char*)d_ws + wbfBytes);
        int* perm  = cnt + 64;
        hipMemsetAsync(out, 0, (size_t)out_size * sizeof(float), stream);
        hipMemsetAsync(cnt, 0, 64, stream);
        prep_kernel<<<576, 256, 0, stream>>>(roi, cnt, perm, Wreg, Wcls, Wbf);
        gemm_r3_kernel<<<528, 512, 0, stream>>>(feats, Wbf, breg, bcls, cnt, perm, out);
    } else if (ws_size >= need_t3) {
        int* counts = (int*)d_ws;
        int* ranks  = counts + 8;
        int* perm   = counts + 64;
        hipMemsetAsync(counts, 0, 16 * sizeof(int), stream);
        hist_kernel<<<NB / 256, 256, 0, stream>>>(roi, counts);
        scatter_kernel<<<NB / 256, 256, 0, stream>>>(roi, counts, ranks, perm);
        gemm_kernel<<<MAXT, 256, 0, stream>>>(feats, Wreg, breg, Wcls, bcls, counts, perm, out, 0);
    } else {
        fallback_kernel<<<NB, 64, 0, stream>>>(feats, roi, Wreg, breg, Wcls, bcls, out);
    }
}

// Round 20
// 70.593 us; speedup vs baseline: 1.3576x; 1.1089x over previous
//
#include <hip/hip_runtime.h>
#include <hip/hip_bf16.h>

#define NB   16384
#define NG   8
#define ND   2048
#define NR   6
#define NKC  48
#define NOUT 54
#define NT32 (NB / 32 + NG)       // 520 tiles of 32 samples
#define LROW 136                  // tier-3 fallback gemm
#define BM   32
#define KC   128
#define NCH  (ND / KC)
#define MAXT (NB / BM + NG)

typedef __attribute__((ext_vector_type(8))) short short8_t;
typedef __attribute__((ext_vector_type(4))) float f32x4;

__device__ __forceinline__ unsigned short f2bf(float x) {
    union { float f; unsigned u; } v; v.f = x;
    unsigned r = v.u + 0x7FFFu + ((v.u >> 16) & 1u);   // RNE
    return (unsigned short)(r >> 16);
}

__device__ __forceinline__ short8_t cvt8(float4 a, float4 b) {
    short8_t s;
    s[0] = (short)f2bf(a.x); s[1] = (short)f2bf(a.y);
    s[2] = (short)f2bf(a.z); s[3] = (short)f2bf(a.w);
    s[4] = (short)f2bf(b.x); s[5] = (short)f2bf(b.y);
    s[6] = (short)f2bf(b.z); s[7] = (short)f2bf(b.w);
    return s;
}

__device__ __forceinline__ short8_t as_s8(float4 v) {
    union { float4 f; short8_t s; } u; u.f = v; return u.s;
}

#define WAITV(N) do { asm volatile("s_waitcnt vmcnt(" #N ")" ::: "memory"); \
                      __builtin_amdgcn_sched_barrier(0); } while (0)

// ---- histogram (tier-3) ----
__global__ void hist_kernel(const int* __restrict__ roi, int* __restrict__ counts) {
    int i = blockIdx.x * 256 + threadIdx.x;
    int g = roi[i];
    int lane = threadIdx.x & 63;
    #pragma unroll
    for (int gg = 0; gg < NG; ++gg) {
        unsigned long long m = __ballot(g == gg);
        if (m && lane == (int)(__ffsll((unsigned long long)m) - 1))
            atomicAdd(&counts[gg], (int)__popcll(m));
    }
}

// ---- scatter into packed regions (tier-3) ----
__global__ void scatter_kernel(const int* __restrict__ roi, const int* __restrict__ counts,
                               int* __restrict__ ranks, int* __restrict__ perm) {
    int off[NG];
    int acc = 0;
    #pragma unroll
    for (int gg = 0; gg < NG; ++gg) { off[gg] = acc; acc += counts[gg]; }
    int i = blockIdx.x * 256 + threadIdx.x;
    int g = roi[i];
    int lane = threadIdx.x & 63;
    #pragma unroll
    for (int gg = 0; gg < NG; ++gg) {
        unsigned long long m = __ballot(g == gg);
        if (!m) continue;
        int leader = (int)(__ffsll((unsigned long long)m) - 1);
        int base = 0;
        if (lane == leader) base = atomicAdd(&ranks[gg], (int)__popcll(m));
        base = __shfl(base, leader);
        if (g == gg) {
            int rank = (int)__popcll(m & ((1ull << lane) - 1ull));
            perm[off[gg] + base + rank] = i;
        }
    }
}

// ---- merged pre-pass: blocks 0..63 scatter roi; 64..575 build the W blob ----
// blob unit u (16B): l=u&63, q=(u>>6)&7, c=(u>>9)&31, g=u>>14; n=q>>1, ks=q&1
// content = W[g][n*16 + (l&15)][c*64 + ks*32 + (l>>4)*8 .. +8)
__global__ void prep_kernel(const int* __restrict__ roi, int* __restrict__ cnt,
                            int* __restrict__ perm,
                            const float* __restrict__ Wreg, const float* __restrict__ Wcls,
                            short* __restrict__ Wbf) {
    if (blockIdx.x < 64) {
        int i = blockIdx.x * 256 + threadIdx.x;
        int g = roi[i];
        int lane = threadIdx.x & 63;
        #pragma unroll
        for (int gg = 0; gg < NG; ++gg) {
            unsigned long long m = __ballot(g == gg);
            if (!m) continue;
            int leader = (int)(__ffsll((unsigned long long)m) - 1);
            int base = 0;
            if (lane == leader) base = atomicAdd(&cnt[gg], (int)__popcll(m));
            base = __shfl(base, leader);
            if (g == gg) {
                int rank = (int)__popcll(m & ((1ull << lane) - 1ull));
                perm[gg * NB + base + rank] = i;
            }
        }
    } else {
        int u = (blockIdx.x - 64) * 256 + threadIdx.x;   // 131072 units
        int l = u & 63;
        int q = (u >> 6) & 7;
        int c = (u >> 9) & 31;
        int g = u >> 14;
        int n = q >> 1, ks = q & 1;
        int row = n * 16 + (l & 15);
        int k   = c * 64 + ks * 32 + (l >> 4) * 8;
        short8_t v = {0, 0, 0, 0, 0, 0, 0, 0};
        if (row < NOUT) {
            const float* s = (row < NR) ? Wreg + (size_t)(g * NR + row) * ND + k
                                        : Wcls + (size_t)(g * NKC + row - NR) * ND + k;
            float4 a = *(const float4*)s;
            float4 b = *(const float4*)(s + 4);
            v = cvt8(a, b);
        }
        *(short8_t*)(Wbf + (size_t)u * 8) = v;
    }
}

// ---- primary: M=32/wave K-split-4 GEMM, inline-asm pinned plain loads ----
// 520 blocks x 4 waves; wave w = K-quarter kh does 8 chunks of KC=64 for the
// block's 32 samples. Per chunk: 8 A + 8 B global_load_dwordx4 (asm-pinned),
// double-buffered x/y, WAITV(16) steady / 0 tail. B issue = 8KB/sample (half
// of R11). No LDS in loop; waves 1..3 park partials, wave 0 reduces + bias +
// scatter (deterministic fixed-order sum).
__launch_bounds__(256, 2)
__global__ void gemm32_kernel(const float* __restrict__ feats,
                              const short* __restrict__ Wbf,
                              const float* __restrict__ breg, const float* __restrict__ bcls,
                              const int* __restrict__ counts, const int* __restrict__ perm,
                              float* __restrict__ out) {
    __shared__ float sacc[3][32][66];   // +2 pad
    __shared__ int sRow[32];

    int tid = threadIdx.x, kh = tid >> 6, l = tid & 63, lr = l & 15, lq = l >> 4;
    int t = blockIdx.x;

    int ts[NG + 1]; ts[0] = 0;
    #pragma unroll
    for (int gg = 0; gg < NG; ++gg) ts[gg + 1] = ts[gg] + ((counts[gg] + 31) >> 5);
    if (t >= ts[NG]) return;
    int g = 0;
    #pragma unroll
    for (int gg = 0; gg < NG; ++gg) if (t >= ts[gg + 1]) g = gg + 1;
    int gcnt  = counts[g];
    int rbase = (t - ts[g]) * 32;
    int nvalid = gcnt - rbase; if (nvalid > 32) nvalid = 32;

    if (tid < 32) {
        int r = rbase + tid;
        if (r >= gcnt) r = gcnt - 1;   // clamp; stores masked later
        sRow[tid] = perm[g * NB + r];
    }
    __syncthreads();

    const char* aB0 = (const char*)(feats + (size_t)sRow[lr] * ND      + kh * 512 + lq * 8);
    const char* aB1 = (const char*)(feats + (size_t)sRow[16 + lr] * ND + kh * 512 + lq * 8);
    const char* bB  = (const char*)(Wbf + (size_t)g * 131072 + (size_t)kh * 8 * 4096 + l * 8);

    f32x4 acc0 = {0,0,0,0}, acc1 = {0,0,0,0}, acc2 = {0,0,0,0}, acc3 = {0,0,0,0};
    f32x4 acc4 = {0,0,0,0}, acc5 = {0,0,0,0}, acc6 = {0,0,0,0}, acc7 = {0,0,0,0};
    float4 xa0, xa1, xa2, xa3, xa4, xa5, xa6, xa7;
    float4 ya0, ya1, ya2, ya3, ya4, ya5, ya6, ya7;
    float4 xb0, xb1, xb2, xb3, xb4, xb5, xb6, xb7;
    float4 yb0, yb1, yb2, yb3, yb4, yb5, yb6, yb7;

#define ISSUE(cc, P) do {                                                               \
        const char* a_ = aB0 + (cc) * 256;                                              \
        asm volatile("global_load_dwordx4 %0, %1, off"            : "=v"(P##a0) : "v"(a_) : "memory"); \
        asm volatile("global_load_dwordx4 %0, %1, off offset:16"  : "=v"(P##a1) : "v"(a_) : "memory"); \
        asm volatile("global_load_dwordx4 %0, %1, off offset:128" : "=v"(P##a2) : "v"(a_) : "memory"); \
        asm volatile("global_load_dwordx4 %0, %1, off offset:144" : "=v"(P##a3) : "v"(a_) : "memory"); \
        const char* a2_ = aB1 + (cc) * 256;                                             \
        asm volatile("global_load_dwordx4 %0, %1, off"            : "=v"(P##a4) : "v"(a2_) : "memory"); \
        asm volatile("global_load_dwordx4 %0, %1, off offset:16"  : "=v"(P##a5) : "v"(a2_) : "memory"); \
        asm volatile("global_load_dwordx4 %0, %1, off offset:128" : "=v"(P##a6) : "v"(a2_) : "memory"); \
        asm volatile("global_load_dwordx4 %0, %1, off offset:144" : "=v"(P##a7) : "v"(a2_) : "memory"); \
        const char* b_  = bB + (cc) * 8192;                                             \
        const char* b2_ = b_ + 4096;                                                    \
        asm volatile("global_load_dwordx4 %0, %1, off"             : "=v"(P##b0) : "v"(b_)  : "memory"); \
        asm volatile("global_load_dwordx4 %0, %1, off offset:1024" : "=v"(P##b1) : "v"(b_)  : "memory"); \
        asm volatile("global_load_dwordx4 %0, %1, off offset:2048" : "=v"(P##b2) : "v"(b_)  : "memory"); \
        asm volatile("global_load_dwordx4 %0, %1, off offset:3072" : "=v"(P##b3) : "v"(b_)  : "memory"); \
        asm volatile("global_load_dwordx4 %0, %1, off"             : "=v"(P##b4) : "v"(b2_) : "memory"); \
        asm volatile("global_load_dwordx4 %0, %1, off offset:1024" : "=v"(P##b5) : "v"(b2_) : "memory"); \
        asm volatile("global_load_dwordx4 %0, %1, off offset:2048" : "=v"(P##b6) : "v"(b2_) : "memory"); \
        asm volatile("global_load_dwordx4 %0, %1, off offset:3072" : "=v"(P##b7) : "v"(b2_) : "memory"); \
    } while (0)

#define CMP(P) do {                                                                     \
        short8_t af00 = cvt8(P##a0, P##a1), af01 = cvt8(P##a2, P##a3);                  \
        short8_t af10 = cvt8(P##a4, P##a5), af11 = cvt8(P##a6, P##a7);                  \
        acc0 = __builtin_amdgcn_mfma_f32_16x16x32_bf16(af00, as_s8(P##b0), acc0, 0, 0, 0); \
        acc1 = __builtin_amdgcn_mfma_f32_16x16x32_bf16(af00, as_s8(P##b2), acc1, 0, 0, 0); \
        acc2 = __builtin_amdgcn_mfma_f32_16x16x32_bf16(af00, as_s8(P##b4), acc2, 0, 0, 0); \
        acc3 = __builtin_amdgcn_mfma_f32_16x16x32_bf16(af00, as_s8(P##b6), acc3, 0, 0, 0); \
        acc4 = __builtin_amdgcn_mfma_f32_16x16x32_bf16(af10, as_s8(P##b0), acc4, 0, 0, 0); \
        acc5 = __builtin_amdgcn_mfma_f32_16x16x32_bf16(af10, as_s8(P##b2), acc5, 0, 0, 0); \
        acc6 = __builtin_amdgcn_mfma_f32_16x16x32_bf16(af10, as_s8(P##b4), acc6, 0, 0, 0); \
        acc7 = __builtin_amdgcn_mfma_f32_16x16x32_bf16(af10, as_s8(P##b6), acc7, 0, 0, 0); \
        acc0 = __builtin_amdgcn_mfma_f32_16x16x32_bf16(af01, as_s8(P##b1), acc0, 0, 0, 0); \
        acc1 = __builtin_amdgcn_mfma_f32_16x16x32_bf16(af01, as_s8(P##b3), acc1, 0, 0, 0); \
        acc2 = __builtin_amdgcn_mfma_f32_16x16x32_bf16(af01, as_s8(P##b5), acc2, 0, 0, 0); \
        acc3 = __builtin_amdgcn_mfma_f32_16x16x32_bf16(af01, as_s8(P##b7), acc3, 0, 0, 0); \
        acc4 = __builtin_amdgcn_mfma_f32_16x16x32_bf16(af11, as_s8(P##b1), acc4, 0, 0, 0); \
        acc5 = __builtin_amdgcn_mfma_f32_16x16x32_bf16(af11, as_s8(P##b3), acc5, 0, 0, 0); \
        acc6 = __builtin_amdgcn_mfma_f32_16x16x32_bf16(af11, as_s8(P##b5), acc6, 0, 0, 0); \
        acc7 = __builtin_amdgcn_mfma_f32_16x16x32_bf16(af11, as_s8(P##b7), acc7, 0, 0, 0); \
    } while (0)

    ISSUE(0, x); ISSUE(1, y);          // 32 loads in flight
    WAITV(16); CMP(x); ISSUE(2, x);    // chunk 0 landed; 1,2 in flight
    WAITV(16); CMP(y); ISSUE(3, y);
    WAITV(16); CMP(x); ISSUE(4, x);
    WAITV(16); CMP(y); ISSUE(5, y);
    WAITV(16); CMP(x); ISSUE(6, x);
    WAITV(16); CMP(y); ISSUE(7, y);
    WAITV(16); CMP(x);
    WAITV(0);  CMP(y);
#undef ISSUE
#undef CMP

    // waves 1..3 park partials in LDS
    if (kh > 0) {
        #pragma unroll
        for (int mt = 0; mt < 2; ++mt) {
            #pragma unroll
            for (int n = 0; n < 4; ++n) {
                f32x4 v = (mt == 0)
                    ? ((n == 0) ? acc0 : (n == 1) ? acc1 : (n == 2) ? acc2 : acc3)
                    : ((n == 0) ? acc4 : (n == 1) ? acc5 : (n == 2) ? acc6 : acc7);
                #pragma unroll
                for (int j = 0; j < 4; ++j)
                    sacc[kh - 1][mt * 16 + lq * 4 + j][n * 16 + lr] = v[j];
            }
        }
    }
    __syncthreads();

    if (kh == 0) {
        const int B6 = NB * NR;
        #pragma unroll
        for (int mt = 0; mt < 2; ++mt) {
            #pragma unroll
            for (int n = 0; n < 4; ++n) {
                f32x4 a = (mt == 0)
                    ? ((n == 0) ? acc0 : (n == 1) ? acc1 : (n == 2) ? acc2 : acc3)
                    : ((n == 0) ? acc4 : (n == 1) ? acc5 : (n == 2) ? acc6 : acc7);
                int col = n * 16 + lr;
                if (col < NOUT) {
                    float bias = (col < NR) ? breg[g * NR + col] : bcls[g * NKC + (col - NR)];
                    #pragma unroll
                    for (int j = 0; j < 4; ++j) {
                        int row = mt * 16 + lq * 4 + j;
                        if (row < nvalid) {
                            float v = a[j] + sacc[0][row][col] + sacc[1][row][col]
                                           + sacc[2][row][col] + bias;
                            int s2 = sRow[row];
                            if (col < NR) out[s2 * NR + col] = v;
                            else          out[B6 + s2 * NKC + (col - NR)] = v;
                        }
                    }
                }
            }
        }
    }
}

// ---- tier-3 GEMM (proven R3 path, no ws blob needed) ----
__launch_bounds__(256, 3)
__global__ void gemm_kernel(const float* __restrict__ feats,
                            const float* __restrict__ Wreg, const float* __restrict__ breg,
                            const float* __restrict__ Wcls, const float* __restrict__ bcls,
                            const int* __restrict__ counts, const int* __restrict__ perm,
                            float* __restrict__ out, int stride) {
    __shared__ __align__(16) short Bsh[2][64][LROW];
    __shared__ int sRow[BM];

    int ts[NG + 1]; ts[0] = 0;
    int off[NG]; int acc = 0;
    #pragma unroll
    for (int gg = 0; gg < NG; ++gg) {
        int c = counts[gg];
        off[gg] = stride ? gg * stride : acc;
        acc += c;
        ts[gg + 1] = ts[gg] + (c + BM - 1) / BM;
    }
    int b = blockIdx.x;
    if (b >= ts[NG]) return;
    int g = 0;
    #pragma unroll
    for (int gg = 0; gg < NG; ++gg) if (b >= ts[gg + 1]) g = gg + 1;
    int gcnt  = counts[g];
    int goff  = off[g];
    int rbase = (b - ts[g]) * BM;
    int nvalid = gcnt - rbase; if (nvalid > BM) nvalid = BM;

    int tid = threadIdx.x;
    if (tid < BM) {
        int r = rbase + tid;
        if (r >= gcnt) r = gcnt - 1;
        sRow[tid] = perm[goff + r];
    }
    __syncthreads();

    int rB = tid >> 2;
    int cq = tid & 3;
    const float* wsrc = nullptr;
    if (rB < NR)        wsrc = Wreg + ((size_t)g * NR + rB) * ND + cq * 32;
    else if (rB < NOUT) wsrc = Wcls + ((size_t)g * NKC + (rB - NR)) * ND + cq * 32;

    int w = tid >> 6, l = tid & 63, lr = l & 15, lq = l >> 4;
    int mt = w & 1, nh = w >> 1;
    const float* aptr = feats + (size_t)sRow[mt * 16 + lr] * ND + lq * 8;
    const short* brp = (const short*)&Bsh[0][0][0] + (nh * 32 + lr) * LROW + lq * 8;

    f32x4 acc0 = {0, 0, 0, 0}, acc1 = {0, 0, 0, 0};
    float4 rb[8];

    if (wsrc) {
        #pragma unroll
        for (int i = 0; i < 8; ++i) rb[i] = *(const float4*)(wsrc + 4 * i);
    } else {
        #pragma unroll
        for (int i = 0; i < 8; ++i) rb[i] = make_float4(0.f, 0.f, 0.f, 0.f);
    }
    {
        short* bw = &Bsh[0][rB][cq * 32];
        #pragma unroll
        for (int j = 0; j < 4; ++j) *(short8_t*)(bw + 8 * j) = cvt8(rb[2 * j], rb[2 * j + 1]);
    }
    __syncthreads();

    #pragma unroll
    for (int c = 0; c < NCH; ++c) {
        const int cur = c & 1, nxt = cur ^ 1;
        if (c + 1 < NCH && wsrc) {
            const float* s = wsrc + (c + 1) * KC;
            #pragma unroll
            for (int i = 0; i < 8; ++i) rb[i] = *(const float4*)(s + 4 * i);
        }
        const short* bp = brp + cur * (64 * LROW);
        const float* ap = aptr + c * KC;
        #pragma unroll
        for (int ks = 0; ks < 4; ++ks) {
            float4 a0 = *(const float4*)(ap + ks * 32);
            float4 a1 = *(const float4*)(ap + ks * 32 + 4);
            short8_t af = cvt8(a0, a1);
            short8_t b0 = *(const short8_t*)(bp + ks * 32);
            short8_t b1 = *(const short8_t*)(bp + 16 * LROW + ks * 32);
            acc0 = __builtin_amdgcn_mfma_f32_16x16x32_bf16(af, b0, acc0, 0, 0, 0);
            acc1 = __builtin_amdgcn_mfma_f32_16x16x32_bf16(af, b1, acc1, 0, 0, 0);
        }
        if (c + 1 < NCH && wsrc) {
            short* bw = &Bsh[nxt][rB][cq * 32];
            #pragma unroll
            for (int j = 0; j < 4; ++j) *(short8_t*)(bw + 8 * j) = cvt8(rb[2 * j], rb[2 * j + 1]);
        } else if (c + 1 < NCH) {
            short8_t z = {0,0,0,0,0,0,0,0};
            short* bw = &Bsh[nxt][rB][cq * 32];
            #pragma unroll
            for (int j = 0; j < 4; ++j) *(short8_t*)(bw + 8 * j) = z;
        }
        __syncthreads();
    }

    const int B6 = NB * NR;
    #pragma unroll
    for (int n = 0; n < 2; ++n) {
        f32x4 v = n ? acc1 : acc0;
        int col = nh * 32 + n * 16 + lr;
        if (col < NOUT) {
            #pragma unroll
            for (int j = 0; j < 4; ++j) {
                int row = mt * 16 + lq * 4 + j;
                if (row < nvalid) {
                    int smp = sRow[row];
                    if (col < NR) out[smp * NR + col] = v[j] + breg[g * NR + col];
                    else          out[B6 + smp * NKC + (col - NR)] = v[j] + bcls[g * NKC + (col - NR)];
                }
            }
        }
    }
}

// ---- tier-4: exact fp32, one wave per sample ----
__global__ void fallback_kernel(const float* __restrict__ feats, const int* __restrict__ roi,
                                const float* __restrict__ Wreg, const float* __restrict__ breg,
                                const float* __restrict__ Wcls, const float* __restrict__ bcls,
                                float* __restrict__ out) {
    int i = blockIdx.x;
    int lane = threadIdx.x;
    int g = roi[i];
    const float* frow = feats + (size_t)i * ND;
    float f[32];
    #pragma unroll
    for (int q = 0; q < 32; ++q) f[q] = frow[lane + 64 * q];
    for (int o = 0; o < NOUT; ++o) {
        const float* wrow = (o < NR) ? Wreg + ((size_t)g * NR + o) * ND
                                     : Wcls + ((size_t)g * NKC + (o - NR)) * ND;
        float p = 0.f;
        #pragma unroll
        for (int q = 0; q < 32; ++q) p += f[q] * wrow[lane + 64 * q];
        #pragma unroll
        for (int s = 32; s; s >>= 1) p += __shfl_xor(p, s);
        if (lane == 0) {
            if (o < NR) out[i * NR + o] = p + breg[g * NR + o];
            else        out[NB * NR + i * NKC + (o - NR)] = p + bcls[g * NKC + (o - NR)];
        }
    }
}

extern "C" void kernel_launch(void* const* d_in, const int* in_sizes, int n_in,
                              void* d_out, int out_size, void* d_ws, size_t ws_size,
                              hipStream_t stream) {
    const float* feats = (const float*)d_in[0];
    const int*   roi   = (const int*)d_in[1];
    const float* Wreg  = (const float*)d_in[2];
    const float* breg  = (const float*)d_in[3];
    const float* Wcls  = (const float*)d_in[4];
    const float* bcls  = (const float*)d_in[5];
    float* out = (float*)d_out;

    const size_t wbfBytes = (size_t)NG * 131072 * 2;              // 2 MB blob
    const size_t need_t1 = wbfBytes + 256 + (size_t)NG * NB * 4;  // blob + fixed-stride perm
    const size_t need_t3 = 256 + (size_t)NB * 4;                  // packed-perm path

    if (ws_size >= need_t1) {
        short* Wbf = (short*)d_ws;
        int* cnt   = (int*)((char*)d_ws + wbfBytes);
        int* perm  = cnt + 64;
        hipMemsetAsync(cnt, 0, 64, stream);
        prep_kernel<<<576, 256, 0, stream>>>(roi, cnt, perm, Wreg, Wcls, Wbf);
        gemm32_kernel<<<NT32, 256, 0, stream>>>(feats, Wbf, breg, bcls, cnt, perm, out);
    } else if (ws_size >= need_t3) {
        int* counts = (int*)d_ws;
        int* ranks  = counts + 8;
        int* perm   = counts + 64;
        hipMemsetAsync(counts, 0, 16 * sizeof(int), stream);
        hist_kernel<<<NB / 256, 256, 0, stream>>>(roi, counts);
        scatter_kernel<<<NB / 256, 256, 0, stream>>>(roi, counts, ranks, perm);
        gemm_kernel<<<MAXT, 256, 0, stream>>>(feats, Wreg, breg, Wcls, bcls, counts, perm, out, 0);
    } else {
        fallback_kernel<<<NB, 64, 0, stream>>>(feats, roi, Wreg, breg, Wcls, bcls, out);
    }
}